// Round 5
// baseline (911.804 us; speedup 1.0000x reference)
//
#include <hip/hip_runtime.h>
#include <cstdint>
#include <cstddef>

#define B_ 64
#define N_ 16384
#define C_ 10
#define D_ 8
#define E_ 16
#define NTB_ 4                    // n per chunk = one MFMA K-quad (4n x 8d = K32)
#define NCHK_ 4                   // chunks per block
#define NPB_ (NTB_ * NCHK_)       // 16 n per block
#define GRID_ (N_ / NPB_)         // 1024 blocks
#define SVOL_ (B_ * C_ * E_)      // 10240 floats
#define WCH_ (NTB_ * C_ * E_ * 4) // 2560 u32 per W chunk

typedef __attribute__((ext_vector_type(8))) short short8;
typedef __attribute__((ext_vector_type(4))) float f32x4;

__device__ __forceinline__ uint32_t f2bf(float f) {
  uint32_t u = __builtin_bit_cast(uint32_t, f);
  return (u + 0x7fffu + ((u >> 16) & 1u)) >> 16;   // RNE
}
__device__ __forceinline__ uint32_t pack2(float lo, float hi) {
  return f2bf(lo) | (f2bf(hi) << 16);
}

// ---------------------------------------------------------------------------
// One routing pass. Block = 16 n x all 64 b, 4 waves; wave wv owns b-tile
// b = wv*16 + (lane&15). K-quad MFMA: lane-group kg = lane>>4 holds n-sub
// kg's k-slots (verified by round-4's lanes<16 == k 0..7 scheme):
//   A[row=e][k=8*kg+d] = W[n0+kg, c, d, e]
//   B[k=8*kg+d][col=b] = x[b, n0+kg, d]
//   D[row=e][col=b]: b=lane&15, e=(lane>>4)*4+reg
// ITER 0: no softmax -> one MFMA accumulates all 4 n of the quad (full K).
// ITER 1: per n-sub j, mask B to k-group j (cndmask); softmax phase computes
// logits and DISCARDS u (regs!), accumulate phase re-issues the MFMAs.
// ---------------------------------------------------------------------------
template <int ITER>
__global__ __launch_bounds__(256, 3) void accum_kernel(
    const float* __restrict__ x,     // [B][N][D]
    const float* __restrict__ W,     // [N][C][D][E]
    const float* __restrict__ vacc,  // [B][C][E]
    float* __restrict__ scopy,       // [ncopy][B][C][E]
    int ncopy)
{
  __shared__ uint32_t wbuf[2][WCH_];        // [n][c][e][d2]  2 x 10 KB
  __shared__ uint32_t xbuf[NPB_ * B_ * 4];  // [n][b][d2]     16 KB

  const int tid = threadIdx.x;
  const int lane = tid & 63;
  const int wv = tid >> 6;
  const int l15 = lane & 15;
  const int kg = lane >> 4;       // frag k-group / D e-group
  const int n0 = blockIdx.x * NPB_;
  const int b = wv * 16 + l15;

  const short8 kzero = (short8){0, 0, 0, 0, 0, 0, 0, 0};
  const f32x4 fzero = (f32x4){0.f, 0.f, 0.f, 0.f};

  f32x4 vf[C_];
  if (ITER) {
#pragma unroll
    for (int c = 0; c < C_; ++c)
      vf[c] = *(const f32x4*)&vacc[(b * C_ + c) * E_ + kg * 4];
  }

  f32x4 acc[C_];
#pragma unroll
  for (int c = 0; c < C_; ++c) acc[c] = fzero;

  // stage x for all 16 n: xbuf[(nl*B + bb)*4 + d2] = nl*256 + tid
#pragma unroll
  for (int nl = 0; nl < NPB_; ++nl) {
    int bb = tid >> 2, d2 = tid & 3;
    const float* p = x + ((size_t)bb * N_ + n0 + nl) * D_ + d2 * 2;
    xbuf[nl * 256 + tid] = pack2(p[0], p[1]);
  }

  auto stage_w = [&](int pb, int nbase) {
#pragma unroll
    for (int it = 0; it < 10; ++it) {
      int i = it * 256 + tid;          // 0..2559
      int n = i / 640, r = i - n * 640;
      int c = r >> 6, r2 = r & 63;
      int d2 = r2 >> 4, e = r2 & 15;
      const float* p = W + ((size_t)(nbase + n) * C_ + c) * 128 + d2 * 32 + e;
      wbuf[pb][((n * C_ + c) * E_ + e) * 4 + d2] = pack2(p[0], p[16]);
    }
  };

  stage_w(0, n0);
  __syncthreads();

  for (int ch = 0; ch < NCHK_; ++ch) {
    if (ch + 1 < NCHK_) stage_w((ch + 1) & 1, n0 + (ch + 1) * NTB_);
    const uint32_t* wb = wbuf[ch & 1];

    short8 wf[C_];                  // full-wave frag loads (4n packed in K)
#pragma unroll
    for (int c = 0; c < C_; ++c)
      wf[c] = *(const short8*)&wb[((kg * C_ + c) * E_ + l15) * 4];
    short8 xq = *(const short8*)&xbuf[((ch * NTB_ + kg) * B_ + b) * 4];

    if (ITER == 0) {
      // full-K MFMA: D = sum over all 4 n of the quad
#pragma unroll
      for (int c = 0; c < C_; ++c)
        acc[c] = __builtin_amdgcn_mfma_f32_16x16x32_bf16(wf[c], xq, acc[c], 0, 0, 0);
    } else {
#pragma unroll
      for (int j = 0; j < NTB_; ++j) {
        short8 xm = (kg == j) ? xq : kzero;   // B masked to k-group j
        // phase 1: logits + softmax (u discarded)
        float ew[C_];
        float ssum = 0.f;
#pragma unroll
        for (int c = 0; c < C_; ++c) {
          f32x4 u = __builtin_amdgcn_mfma_f32_16x16x32_bf16(wf[c], xm, fzero, 0, 0, 0);
          float t = u[0] * vf[c][0] + u[1] * vf[c][1] +
                    u[2] * vf[c][2] + u[3] * vf[c][3];
          t += __shfl_xor(t, 16);
          t += __shfl_xor(t, 32);   // full e-sum, all lanes
          ew[c] = __expf(t);
          ssum += ew[c];
        }
        float inv = __builtin_amdgcn_rcpf(ssum);
        // phase 2: recompute u, accumulate
#pragma unroll
        for (int c = 0; c < C_; ++c) {
          float cw = ew[c] * inv;
          f32x4 u = __builtin_amdgcn_mfma_f32_16x16x32_bf16(wf[c], xm, fzero, 0, 0, 0);
          acc[c][0] = fmaf(cw, u[0], acc[c][0]);
          acc[c][1] = fmaf(cw, u[1], acc[c][1]);
          acc[c][2] = fmaf(cw, u[2], acc[c][2]);
          acc[c][3] = fmaf(cw, u[3], acc[c][3]);
        }
      }
    }
    __syncthreads();
  }

  // flush: thread owns s[b][c][kg*4..+3]
  const float scale = (ITER == 0) ? 0.1f : 1.0f;
  float* sc = scopy + (size_t)(blockIdx.x & (ncopy - 1)) * SVOL_;
#pragma unroll
  for (int c = 0; c < C_; ++c)
#pragma unroll
    for (int r = 0; r < 4; ++r)
      atomicAdd(&sc[(b * C_ + c) * E_ + kg * 4 + r], acc[c][r] * scale);
}

// ---------------------------------------------------------------------------
// Reduce striped s copies, apply squash. 16 consecutive lanes = one capsule.
// MODE 0: vacc = v (re-zero stripes)  MODE 1: vacc += v (re-zero)
// MODE 2: out = v (no re-zero; launch-start memset covers next replay)
// ---------------------------------------------------------------------------
template <int MODE>
__global__ __launch_bounds__(256) void squash_kernel(
    float* __restrict__ scopy, int ncopy,
    float* __restrict__ vacc, float* __restrict__ out)
{
  int t = blockIdx.x * 256 + threadIdx.x;  // 0..10239
  float sv = 0.f;
  for (int k = 0; k < ncopy; ++k) {
    sv += scopy[(size_t)k * SVOL_ + t];
    if (MODE != 2) scopy[(size_t)k * SVOL_ + t] = 0.f;
  }
  float sq = sv * sv;
  sq += __shfl_xor(sq, 1);
  sq += __shfl_xor(sq, 2);
  sq += __shfl_xor(sq, 4);
  sq += __shfl_xor(sq, 8);
  float scale = sq / (1.f + sq) * rsqrtf(sq + 1e-7f);
  float v = scale * sv;
  if (MODE == 0)      vacc[t] = v;
  else if (MODE == 1) vacc[t] += v;
  else                out[t] = v;
}

extern "C" void kernel_launch(void* const* d_in, const int* in_sizes, int n_in,
                              void* d_out, int out_size, void* d_ws, size_t ws_size,
                              hipStream_t stream)
{
  const float* x = (const float*)d_in[0];  // [64][16384][8]
  const float* W = (const float*)d_in[1];  // [16384][10][8][16]
  float* out = (float*)d_out;              // [64][10][16]

  int ncopy = 64;
  while (ncopy > 1 && (size_t)(ncopy + 1) * SVOL_ * sizeof(float) > ws_size)
    ncopy >>= 1;
  float* s_ws = (float*)d_ws;
  float* vacc = s_ws + (size_t)ncopy * SVOL_;
  const size_t s_bytes = (size_t)ncopy * SVOL_ * sizeof(float);

  // single memset per launch; squash<0>/<1> re-zero stripes between passes
  hipMemsetAsync(s_ws, 0, s_bytes, stream);

  // pass 0: uniform c=0.1 -> s0 -> v0
  accum_kernel<0><<<GRID_, 256, 0, stream>>>(x, W, vacc, s_ws, ncopy);
  squash_kernel<0><<<SVOL_ / 256, 256, 0, stream>>>(s_ws, ncopy, vacc, out);

  // pass 1: logits = u.v0 -> s1 -> v1; vacc = v0 + v1
  accum_kernel<1><<<GRID_, 256, 0, stream>>>(x, W, vacc, s_ws, ncopy);
  squash_kernel<1><<<SVOL_ / 256, 256, 0, stream>>>(s_ws, ncopy, vacc, out);

  // pass 2: logits = u.(v0+v1) -> v2 = output
  accum_kernel<1><<<GRID_, 256, 0, stream>>>(x, W, vacc, s_ws, ncopy);
  squash_kernel<2><<<SVOL_ / 256, 256, 0, stream>>>(s_ws, ncopy, vacc, out);
}